// Round 11
// baseline (79.432 us; speedup 1.0000x reference)
//
#include <hip/hip_runtime.h>
#include <stdint.h>

typedef unsigned short ushort_t;
typedef short short8 __attribute__((ext_vector_type(8)));
typedef float float4_ __attribute__((ext_vector_type(4)));
typedef unsigned short u16x8 __attribute__((ext_vector_type(8)));

#define INF_ 10000.0f
#define BATCH 8
#define SEQLEN 512
#define HIDDEN 1024
#define HEADS 12
#define HEAD_SIZE 64
#define NOUT 1536          // HEADS * 2 * HEAD_SIZE
#define MROWS 4096         // BATCH * SEQLEN
#define BH 96              // BATCH * HEADS
#define LOGITS_N 25165824  // (8,12,512,512)
#define MASK_N   2097152   // (8,1,512,512)

// ---- module-scope device scratch (no dependence on ws_size) ----
__device__ __align__(16) ushort_t g_Wt[(size_t)NOUT * HIDDEN];            // 3 MB
__device__ __align__(16) ushort_t g_Q[(size_t)BH * SEQLEN * HEAD_SIZE];   // 6 MB
__device__ __align__(16) ushort_t g_K[(size_t)BH * SEQLEN * HEAD_SIZE];   // 6 MB
__device__ __align__(16) float    g_tab[SEQLEN * 32 * 2];                 // 128 KB

__device__ __forceinline__ ushort_t f2bf(float f) {
    unsigned u = __builtin_bit_cast(unsigned, f);
    unsigned r = u + 0x7FFFu + ((u >> 16) & 1u);
    return (ushort_t)(r >> 16);
}

// ---- robust mask decoding (sniff dtype; mask is all-ones by construction) ----
__device__ __forceinline__ unsigned mask_code(const void* m) {
    unsigned u0 = ((const unsigned*)m)[0];
    unsigned u1 = ((const unsigned*)m)[1];
    if (u0 == 0x3F803F80u) return 2;                  // bf16 1.0,1.0
    if (u0 == 0x3F800000u) return 3;                  // fp32 1.0
    if (u0 == 0x01010101u) return 4;                  // int8/bool
    if (u0 == 0x00010001u) return 5;                  // int16
    if (u0 == 1u && u1 == 0u) return 1;               // int64
    return 0;                                         // int32
}
__device__ __forceinline__ float mask_at(const void* m, unsigned code, int i) {
    switch (code) {
        case 1: return (float)((const long long*)m)[i];
        case 2: { unsigned u = (unsigned)((const ushort_t*)m)[i] << 16;
                  return __builtin_bit_cast(float, u); }
        case 3: return ((const float*)m)[i];
        case 4: return (float)((const signed char*)m)[i];
        case 5: return (float)((const short*)m)[i];
        default: return (float)((const int*)m)[i];
    }
}

// ---- transpose + convert W [K=1024][N=1536] fp32 -> Wt [N][K] bf16 ----
__global__ void k_convWt(const float* __restrict__ W) {
    __shared__ ushort_t tile[32][33];
    int bx = blockIdx.x % 48;            // n-tile
    int by = blockIdx.x / 48;            // k-tile
    int tx = threadIdx.x & 31, ty = threadIdx.x >> 5;   // 32 x 8
    #pragma unroll
    for (int i = 0; i < 4; ++i) {
        int k = by * 32 + ty + i * 8;
        int n = bx * 32 + tx;
        tile[ty + i * 8][tx] = f2bf(W[(size_t)k * NOUT + n]);
    }
    __syncthreads();
    #pragma unroll
    for (int i = 0; i < 4; ++i) {
        int n = bx * 32 + ty + i * 8;
        int k = by * 32 + tx;
        g_Wt[(size_t)n * HIDDEN + k] = tile[tx][ty + i * 8];
    }
}

// ---- RoPE sin/cos table ----
__global__ void k_sincos() {
    int i = blockIdx.x * 256 + threadIdx.x;       // 0 .. 16383
    int s = i >> 5, f = i & 31;
    float inv = powf(10000.0f, -(float)(2 * f) / 64.0f);
    float ang = (float)s * inv;
    g_tab[2 * i]     = sinf(ang);
    g_tab[2 * i + 1] = cosf(ang);
}

// ---- mask output plane (fp32): out1[b,0,m,n] = (n<m) || pad>0 ----
__global__ void k_maskout(const void* __restrict__ mask, float* __restrict__ out1) {
    int i8 = blockIdx.x * 256 + threadIdx.x;      // 0 .. 262143
    int base = i8 * 8;
    int b = base >> 18;
    int m = (base >> 9) & 511;
    int n0 = base & 511;
    unsigned mcode = mask_code(mask);
    float mr = mask_at(mask, mcode, b * SEQLEN + m);
    float4_ o0, o1;
    #pragma unroll
    for (int j = 0; j < 8; ++j) {
        float padv = 1.0f - mr * mask_at(mask, mcode, b * SEQLEN + n0 + j);
        float v = ((n0 + j) < m || padv > 0.0f) ? 1.0f : 0.0f;
        if (j < 4) o0[j] = v; else o1[j - 4] = v;
    }
    *(float4_*)(out1 + base)     = o0;
    *(float4_*)(out1 + base + 4) = o1;
}

// ---- GEMM1 (bf16 MFMA) + bias + fused RoPE epilogue -> g_Q/g_K ----
__global__ void __launch_bounds__(256) k_gemm1(const float* __restrict__ A,
                                               const float* __restrict__ bias) {
    __shared__ __align__(16) ushort_t sA[2][128 * 32];
    __shared__ __align__(16) ushort_t sB[2][128 * 32];
    int tid = threadIdx.x;
    int lane = tid & 63, wid = tid >> 6;
    int wm = wid >> 1, wn = wid & 1;
    int bm = (blockIdx.x & 31) * 128;
    int bn = (blockIdx.x >> 5) * 128;

    int arow = tid >> 1, ahalf = tid & 1;
    const float* Aptr = A + (size_t)(bm + arow) * HIDDEN + ahalf * 16;
    auto loadB = [&](int ks, int i) -> short8 {
        int c = tid + i * 256;
        int row = c >> 2, cg = c & 3;
        return *(const short8*)(g_Wt + (size_t)(bn + row) * HIDDEN + ks * 32 + cg * 8);
    };

    float4_ fa[4];
    short8 rb[2];
    #pragma unroll
    for (int q = 0; q < 4; ++q) fa[q] = *(const float4_*)(Aptr + q * 4);
    rb[0] = loadB(0, 0); rb[1] = loadB(0, 1);

    float4_ acc[4][4] = {};
    int cur = 0;
    const int NT = HIDDEN / 32;
    for (int ks = 0; ks < NT; ++ks) {
        u16x8 pk0, pk1;
        #pragma unroll
        for (int j = 0; j < 4; ++j) { pk0[j] = f2bf(fa[0][j]); pk0[j+4] = f2bf(fa[1][j]); }
        #pragma unroll
        for (int j = 0; j < 4; ++j) { pk1[j] = f2bf(fa[2][j]); pk1[j+4] = f2bf(fa[3][j]); }
        *(u16x8*)(sA[cur] + (size_t)arow * 32 + ahalf * 16)     = pk0;
        *(u16x8*)(sA[cur] + (size_t)arow * 32 + ahalf * 16 + 8) = pk1;
        *(short8*)(sB[cur] + (size_t)tid * 8)         = rb[0];
        *(short8*)(sB[cur] + (size_t)(tid + 256) * 8) = rb[1];
        __syncthreads();
        if (ks + 1 < NT) {
            #pragma unroll
            for (int q = 0; q < 4; ++q) fa[q] = *(const float4_*)(Aptr + (ks + 1) * 32 + q * 4);
            rb[0] = loadB(ks + 1, 0); rb[1] = loadB(ks + 1, 1);
        }
        short8 af[4], bfv[4];
        int kofs = (lane >> 4) * 8;
        #pragma unroll
        for (int mf = 0; mf < 4; ++mf)
            af[mf] = *(const short8*)(sA[cur] + (wm * 64 + mf * 16 + (lane & 15)) * 32 + kofs);
        #pragma unroll
        for (int nf = 0; nf < 4; ++nf)
            bfv[nf] = *(const short8*)(sB[cur] + (wn * 64 + nf * 16 + (lane & 15)) * 32 + kofs);
        #pragma unroll
        for (int mf = 0; mf < 4; ++mf)
            #pragma unroll
            for (int nf = 0; nf < 4; ++nf)
                acc[mf][nf] = __builtin_amdgcn_mfma_f32_16x16x32_bf16(af[mf], bfv[nf], acc[mf][nf], 0, 0, 0);
        cur ^= 1;
    }

    // Epilogue (validated map: N=col=lane&15, M=row=(lane>>4)*4+reg);
    // RoPE partner col gn^1 lives in lane^1 -> __shfl_xor.
    #pragma unroll
    for (int nf = 0; nf < 4; ++nf) {
        int gn = bn + wn * 64 + nf * 16 + (lane & 15);
        float bv = bias[gn];
        int head = gn >> 7;
        int isk  = (gn >> 6) & 1;
        int d0 = gn & 63;
        int fi = d0 >> 1;
        float sgn = (gn & 1) ? 1.0f : -1.0f;
        ushort_t* dst = isk ? g_K : g_Q;
        #pragma unroll
        for (int mf = 0; mf < 4; ++mf) {
            int gm0 = bm + wm * 64 + mf * 16 + ((lane >> 4) * 4);
            #pragma unroll
            for (int r = 0; r < 4; ++r) {
                int gm = gm0 + r;
                int s = gm & (SEQLEN - 1);
                int b = gm >> 9;
                float v = acc[mf][nf][r] + bv;
                float p = __shfl_xor(v, 1, 64);
                const float* tc = g_tab + 2 * (s * 32 + fi);
                float sn = tc[0], cs = tc[1];
                float y = v * cs + sgn * p * sn;
                size_t o = (((size_t)(b * HEADS + head)) * SEQLEN + s) * HEAD_SIZE + d0;
                dst[o] = f2bf(y);
            }
        }
    }
}

// ---- GEMM2 (bf16 MFMA): logits fp32 out, fused mask penalty ----
__global__ void __launch_bounds__(256) k_gemm2(const void* __restrict__ mask,
                                               float* __restrict__ out) {
    __shared__ __align__(16) ushort_t sQ[128 * 64];
    __shared__ __align__(16) ushort_t sK[128 * 64];
    __shared__ float sMr[128], sMc[128];
    int tid = threadIdx.x;
    int lane = tid & 63, wid = tid >> 6;
    int blk = blockIdx.x;
    int bh = blk >> 4;
    int t = blk & 15;
    int mt = t >> 2, nt = t & 3;
    int b = bh / HEADS;

    const ushort_t* Qb = g_Q + ((size_t)bh * SEQLEN + mt * 128) * HEAD_SIZE;
    const ushort_t* Kb = g_K + ((size_t)bh * SEQLEN + nt * 128) * HEAD_SIZE;
    #pragma unroll
    for (int i = 0; i < 4; ++i) {
        int c = tid + i * 256;
        *(short8*)(sQ + (size_t)c * 8) = *(const short8*)(Qb + (size_t)c * 8);
        *(short8*)(sK + (size_t)c * 8) = *(const short8*)(Kb + (size_t)c * 8);
    }
    unsigned mcode = mask_code(mask);
    if (tid < 128)      sMr[tid]       = mask_at(mask, mcode, b * SEQLEN + mt * 128 + tid);
    else                sMc[tid - 128] = mask_at(mask, mcode, b * SEQLEN + nt * 128 + (tid - 128));
    __syncthreads();

    int wm = wid >> 1, wn = wid & 1;
    float4_ acc[4][4] = {};
    #pragma unroll
    for (int kk = 0; kk < 2; ++kk) {
        short8 af[4], bfv[4];
        int ko = kk * 32 + (lane >> 4) * 8;
        #pragma unroll
        for (int mf = 0; mf < 4; ++mf)
            af[mf] = *(const short8*)(sQ + (wm * 64 + mf * 16 + (lane & 15)) * 64 + ko);
        #pragma unroll
        for (int nf = 0; nf < 4; ++nf)
            bfv[nf] = *(const short8*)(sK + (wn * 64 + nf * 16 + (lane & 15)) * 64 + ko);
        #pragma unroll
        for (int mf = 0; mf < 4; ++mf)
            #pragma unroll
            for (int nf = 0; nf < 4; ++nf)
                acc[mf][nf] = __builtin_amdgcn_mfma_f32_16x16x32_bf16(af[mf], bfv[nf], acc[mf][nf], 0, 0, 0);
    }

    // Validated C/D map: k-col (N) = lane&15, q-row (M) = (lane>>4)*4 + reg
    size_t obase = (size_t)bh * SEQLEN * SEQLEN;
    #pragma unroll
    for (int mf = 0; mf < 4; ++mf) {
        #pragma unroll
        for (int nf = 0; nf < 4; ++nf) {
            int lcol = wn * 64 + nf * 16 + (lane & 15);
            int lrow0 = wm * 64 + mf * 16 + ((lane >> 4) * 4);
            int gn = nt * 128 + lcol;
            float mc = sMc[lcol];
            #pragma unroll
            for (int r = 0; r < 4; ++r) {
                int lrow = lrow0 + r;
                int gm = mt * 128 + lrow;
                float padv = 1.0f - sMr[lrow] * mc;
                bool tl = gn < gm;
                float v = (acc[mf][nf][r] - padv * INF_ - (tl ? INF_ : 0.0f)) * 0.125f;
                out[obase + (size_t)gm * SEQLEN + gn] = v;
            }
        }
    }
}

extern "C" void kernel_launch(void* const* d_in, const int* in_sizes, int n_in,
                              void* d_out, int out_size, void* d_ws, size_t ws_size,
                              hipStream_t stream) {
    const float* inp = nullptr; const float* W = nullptr;
    const float* bias = nullptr; const void* mask = nullptr;
    for (int i = 0; i < n_in; ++i) {
        switch (in_sizes[i]) {
            case MROWS * HIDDEN:  inp  = (const float*)d_in[i]; break;   // 4194304
            case HIDDEN * NOUT:   W    = (const float*)d_in[i]; break;   // 1572864
            case NOUT:            bias = (const float*)d_in[i]; break;   // 1536
            case BATCH * SEQLEN:  mask = d_in[i]; break;                 // 4096
        }
    }
    if (!inp || !W || !bias || !mask) {
        inp  = (const float*)d_in[0];
        W    = (const float*)d_in[1];
        bias = (const float*)d_in[2];
        mask = d_in[3];
    }
    float* out = (float*)d_out;                    // fp32 output buffer
    (void)d_ws; (void)ws_size;

    k_convWt<<<48 * 32, 256, 0, stream>>>(W);
    k_sincos<<<64, 256, 0, stream>>>();
    k_maskout<<<1024, 256, 0, stream>>>(mask, out + LOGITS_N);
    k_gemm1<<<384, 256, 0, stream>>>(inp, bias);
    k_gemm2<<<16 * BH, 256, 0, stream>>>(mask, out);
}